// Round 1
// baseline (2064.716 us; speedup 1.0000x reference)
//
#include <hip/hip_runtime.h>

typedef unsigned short u16;
typedef unsigned int u32;
typedef short bf16x8 __attribute__((ext_vector_type(8)));
typedef float f32x4 __attribute__((ext_vector_type(4)));

__device__ __forceinline__ u16 f2b(float f) {
  u32 u = __float_as_uint(f);
  u += 0x7fffu + ((u >> 16) & 1u);   // round-to-nearest-even
  return (u16)(u >> 16);
}
__device__ __forceinline__ float b2f(u16 s) {
  return __uint_as_float(((u32)s) << 16);
}

// ---------------- cast x (f32) -> bf16 ----------------
__global__ __launch_bounds__(256) void cast_kernel(const float* __restrict__ x,
                                                   u16* __restrict__ xb, int n4) {
  int i = blockIdx.x * 256 + threadIdx.x;
  if (i >= n4) return;
  float4 v = ((const float4*)x)[i];
  ushort4 u;
  u.x = f2b(v.x); u.y = f2b(v.y); u.z = f2b(v.z); u.w = f2b(v.w);
  ((ushort4*)xb)[i] = u;
}

// ---------------- fill cls rows (token 0) ----------------
__global__ __launch_bounds__(256) void cls_kernel(const float* __restrict__ cls,
                                                  float* __restrict__ h,
                                                  u16* __restrict__ hb) {
  int i = blockIdx.x * 256 + threadIdx.x;  // B*128 threads, 4 elems each
  int b = i >> 7;
  int e = (i & 127) << 2;
  float4 v = *(const float4*)(cls + e);
  long off = (long)b * (25 * 512) + e;
  *(float4*)(h + off) = v;
  ushort4 u;
  u.x = f2b(v.x); u.y = f2b(v.y); u.z = f2b(v.z); u.w = f2b(v.w);
  *(ushort4*)(hb + off) = u;
}

// ---------------- generic grouped GEMM + bias ----------------
// C[row, col] = sum_k A[row*a_stride + g*a_goff + k] * W_g[k, col] + bias_g[col]
// 128x128 tile, 4 waves (each 64x64 = 4x4 frags of 16x16), BK=64.
// A is bf16; W/bias fp32 (converted to bf16 during staging).
// Writes bf16 to Cb always; optionally fp32 to Cf.
__global__ __launch_bounds__(256) void gemm_bias(
    const u16* __restrict__ Abase, long a_stride, long a_goff,
    const float* __restrict__ Wbase, long w_gstride, int ldw,
    const float* __restrict__ biasbase, long bias_gstride,
    u16* __restrict__ Cb, float* __restrict__ Cf, long c_stride, long c_goff,
    int K) {
  __shared__ u16 As[128 * 64];  // [row][k], XOR-swizzled (bits 3..5 of u16 idx)
  __shared__ u16 Bs[128 * 64];  // [col][k] (transposed), XOR-swizzled

  const int tid = threadIdx.x;
  const int lane = tid & 63;
  const int wave = tid >> 6;
  const int wr = wave >> 1, wc = wave & 1;
  const int m0 = blockIdx.x * 128;
  const int n0 = blockIdx.y * 128;
  const int g = blockIdx.z;

  const u16* Ag = Abase + (long)g * a_goff;
  const float* Wg = Wbase + (long)g * w_gstride;
  const float* biasg = biasbase + (long)g * bias_gstride;
  const long cg = (long)g * c_goff;

  const int ar = tid >> 1;           // A staging: row 0..127
  const int aks = (tid & 1) << 5;    // k-seg 0 / 32
  const int bc = tid & 127;          // B staging: col 0..127
  const int bks = (tid >> 7) << 5;   // k-seg 0 / 32

  f32x4 acc[4][4];
#pragma unroll
  for (int m = 0; m < 4; ++m)
#pragma unroll
    for (int n = 0; n < 4; ++n) {
      acc[m][n][0] = 0.f; acc[m][n][1] = 0.f;
      acc[m][n][2] = 0.f; acc[m][n][3] = 0.f;
    }

  for (int k0 = 0; k0 < K; k0 += 64) {
    // ---- global loads (before barrier, overlap with prior compute) ----
    const u16* asrc = Ag + (long)(m0 + ar) * a_stride + k0 + aks;
    uint4 a0 = *(const uint4*)(asrc + 0);
    uint4 a1 = *(const uint4*)(asrc + 8);
    uint4 a2 = *(const uint4*)(asrc + 16);
    uint4 a3 = *(const uint4*)(asrc + 24);

    const float* wsrc = Wg + (long)(k0 + bks) * ldw + n0 + bc;
    u32 pack[16];
#pragma unroll
    for (int i = 0; i < 16; ++i) {
      float f0 = wsrc[(long)(2 * i) * ldw];
      float f1 = wsrc[(long)(2 * i + 1) * ldw];
      pack[i] = (u32)f2b(f0) | ((u32)f2b(f1) << 16);
    }

    __syncthreads();  // previous tile's compute done (LDS free)
    {
      const int abase = ar << 6;
      const int asw = (ar & 7) << 3;
      *(uint4*)&As[(abase + aks + 0) ^ asw] = a0;
      *(uint4*)&As[(abase + aks + 8) ^ asw] = a1;
      *(uint4*)&As[(abase + aks + 16) ^ asw] = a2;
      *(uint4*)&As[(abase + aks + 24) ^ asw] = a3;
      const int bbase = bc << 6;
      const int bsw = (bc & 7) << 3;
#pragma unroll
      for (int i = 0; i < 4; ++i) {
        uint4 w;
        w.x = pack[4 * i + 0]; w.y = pack[4 * i + 1];
        w.z = pack[4 * i + 2]; w.w = pack[4 * i + 3];
        *(uint4*)&Bs[(bbase + bks + 8 * i) ^ bsw] = w;
      }
    }
    __syncthreads();  // tile ready

#pragma unroll
    for (int kk = 0; kk < 64; kk += 32) {
      const int kb = kk + ((lane >> 4) << 3);
      bf16x8 af[4], bfr[4];
#pragma unroll
      for (int m = 0; m < 4; ++m) {
        const int R = (wr << 6) + (m << 4) + (lane & 15);
        af[m] = *(const bf16x8*)&As[((R << 6) + kb) ^ ((R & 7) << 3)];
      }
#pragma unroll
      for (int n = 0; n < 4; ++n) {
        const int Cc = (wc << 6) + (n << 4) + (lane & 15);
        bfr[n] = *(const bf16x8*)&Bs[((Cc << 6) + kb) ^ ((Cc & 7) << 3)];
      }
#pragma unroll
      for (int m = 0; m < 4; ++m)
#pragma unroll
        for (int n = 0; n < 4; ++n)
          acc[m][n] = __builtin_amdgcn_mfma_f32_16x16x32_bf16(af[m], bfr[n],
                                                              acc[m][n], 0, 0, 0);
    }
  }

  // ---- epilogue: C/D layout col=lane&15, row=(lane>>4)*4+j (HW-verified) ----
  const int lcol = lane & 15;
  const int lrow = (lane >> 4) << 2;
#pragma unroll
  for (int n = 0; n < 4; ++n) {
    const int col = n0 + (wc << 6) + (n << 4) + lcol;
    const float bv = biasg[col];
#pragma unroll
    for (int m = 0; m < 4; ++m) {
      const int row = m0 + (wr << 6) + (m << 4) + lrow;
#pragma unroll
      for (int j = 0; j < 4; ++j) {
        const float val = acc[m][n][j] + bv;
        const long off = (long)(row + j) * c_stride + cg + col;
        Cb[off] = f2b(val);
        if (Cf) Cf[off] = val;
      }
    }
  }
}

// ---------------- attention: one block per batch, thread per (head,row) ----
// Reads q/k/v (bf16), writes output (bf16) OVER the k buffer.
__global__ __launch_bounds__(256) void attn_kernel(const u16* __restrict__ q,
                                                   u16* __restrict__ kio,
                                                   const u16* __restrict__ v) {
  __shared__ u16 ks_[25 * 512];
  __shared__ u16 vs_[25 * 512];
  const int b = blockIdx.x;
  const int tid = threadIdx.x;
  const long base = (long)b * 25 * 512;
  const uint4* ksrc = (const uint4*)(kio + base);
  const uint4* vsrc = (const uint4*)(v + base);
  for (int i = tid; i < 1600; i += 256) {
    ((uint4*)ks_)[i] = ksrc[i];
    ((uint4*)vs_)[i] = vsrc[i];
  }
  __syncthreads();
  if (tid < 200) {
    const int hh = tid / 25;
    const int qr = tid % 25;
    const u16* qrow = q + base + (long)qr * 512 + hh * 64;
    float qv[64];
#pragma unroll
    for (int d = 0; d < 64; d += 2) {
      u32 t = *(const u32*)(qrow + d);
      qv[d] = b2f((u16)t);
      qv[d + 1] = b2f((u16)(t >> 16));
    }
    float sc[25];
    float mx = -1e30f;
#pragma unroll
    for (int j = 0; j < 25; ++j) {
      float s = 0.f;
#pragma unroll
      for (int d = 0; d < 64; d += 2) {
        u32 t = *(const u32*)&ks_[j * 512 + hh * 64 + d];
        s += qv[d] * b2f((u16)t) + qv[d + 1] * b2f((u16)(t >> 16));
      }
      s *= 0.125f;  // 1/sqrt(64)
      sc[j] = s;
      mx = fmaxf(mx, s);
    }
    float sum = 0.f;
#pragma unroll
    for (int j = 0; j < 25; ++j) {
      sc[j] = __expf(sc[j] - mx);
      sum += sc[j];
    }
    const float inv = 1.f / sum;
#pragma unroll
    for (int d = 0; d < 64; ++d) qv[d] = 0.f;  // reuse qv as output acc
#pragma unroll
    for (int j = 0; j < 25; ++j) {
      const float w = sc[j];
#pragma unroll
      for (int d = 0; d < 64; d += 2) {
        u32 t = *(const u32*)&vs_[j * 512 + hh * 64 + d];
        qv[d] += w * b2f((u16)t);
        qv[d + 1] += w * b2f((u16)(t >> 16));
      }
    }
    u16* orow = kio + base + (long)qr * 512 + hh * 64;
#pragma unroll
    for (int d = 0; d < 64; d += 2) {
      u32 t = (u32)f2b(qv[d] * inv) | ((u32)f2b(qv[d + 1] * inv) << 16);
      *(u32*)(orow + d) = t;
    }
  }
}

// ---------------- residual + LayerNorm: wave per row ----------------
// h(f32, in/out d_out) += o(bf16); LN; writes f32 back + bf16 shadow to hb.
__global__ __launch_bounds__(256) void ln_kernel(float* __restrict__ h,
                                                 const u16* __restrict__ o,
                                                 const float* __restrict__ g,
                                                 const float* __restrict__ bta,
                                                 u16* __restrict__ hb) {
  const int lane = threadIdx.x & 63;
  const int wave = threadIdx.x >> 6;
  const long row = (long)blockIdx.x * 4 + wave;
  float* hr = h + row * 512;
  const u16* orow = o + row * 512;
  const int base = lane << 3;
  float4 h0 = *(const float4*)(hr + base);
  float4 h1 = *(const float4*)(hr + base + 4);
  uint4 ov = *(const uint4*)(orow + base);
  float y[8];
  y[0] = h0.x + b2f((u16)ov.x); y[1] = h0.y + b2f((u16)(ov.x >> 16));
  y[2] = h0.z + b2f((u16)ov.y); y[3] = h0.w + b2f((u16)(ov.y >> 16));
  y[4] = h1.x + b2f((u16)ov.z); y[5] = h1.y + b2f((u16)(ov.z >> 16));
  y[6] = h1.z + b2f((u16)ov.w); y[7] = h1.w + b2f((u16)(ov.w >> 16));
  float s = 0.f, ss = 0.f;
#pragma unroll
  for (int i = 0; i < 8; ++i) { s += y[i]; ss += y[i] * y[i]; }
#pragma unroll
  for (int off = 32; off > 0; off >>= 1) {
    s += __shfl_down(s, off);
    ss += __shfl_down(ss, off);
  }
  s = __shfl(s, 0);
  ss = __shfl(ss, 0);
  const float mean = s * (1.f / 512.f);
  const float var = ss * (1.f / 512.f) - mean * mean;
  const float rinv = rsqrtf(var + 1e-5f);
  float4 g0 = *(const float4*)(g + base);
  float4 g1 = *(const float4*)(g + base + 4);
  float4 b0 = *(const float4*)(bta + base);
  float4 b1 = *(const float4*)(bta + base + 4);
  float r[8];
  r[0] = (y[0] - mean) * rinv * g0.x + b0.x;
  r[1] = (y[1] - mean) * rinv * g0.y + b0.y;
  r[2] = (y[2] - mean) * rinv * g0.z + b0.z;
  r[3] = (y[3] - mean) * rinv * g0.w + b0.w;
  r[4] = (y[4] - mean) * rinv * g1.x + b1.x;
  r[5] = (y[5] - mean) * rinv * g1.y + b1.y;
  r[6] = (y[6] - mean) * rinv * g1.z + b1.z;
  r[7] = (y[7] - mean) * rinv * g1.w + b1.w;
  float4 w0 = {r[0], r[1], r[2], r[3]};
  float4 w1 = {r[4], r[5], r[6], r[7]};
  *(float4*)(hr + base) = w0;
  *(float4*)(hr + base + 4) = w1;
  uint4 hv;
  hv.x = (u32)f2b(r[0]) | ((u32)f2b(r[1]) << 16);
  hv.y = (u32)f2b(r[2]) | ((u32)f2b(r[3]) << 16);
  hv.z = (u32)f2b(r[4]) | ((u32)f2b(r[5]) << 16);
  hv.w = (u32)f2b(r[6]) | ((u32)f2b(r[7]) << 16);
  *(uint4*)(hb + row * 512 + base) = hv;
}

// ---------------- host launcher ----------------
// d_in order: x, We, be, cls, Wk, bk, Wv, bv, Wq, bq, Wo, bo, ln_g, ln_b
// Workspace plan (needs 100 MiB):
//   hb (bf16 H)   @ 0          : 26,214,400 B
//   kb (bf16 K/AO)@ 26,214,400 : 26,214,400 B   (also aliased as xb pre-layers)
//   vb (bf16 V)   @ 52,428,800 : 26,214,400 B
//   qb (bf16 Q/O) @ 78,643,200 : 26,214,400 B
extern "C" void kernel_launch(void* const* d_in, const int* in_sizes, int n_in,
                              void* d_out, int out_size, void* d_ws, size_t ws_size,
                              hipStream_t stream) {
  const float* x   = (const float*)d_in[0];
  const float* We  = (const float*)d_in[1];
  const float* be  = (const float*)d_in[2];
  const float* cls = (const float*)d_in[3];
  const float* Wk  = (const float*)d_in[4];
  const float* bk  = (const float*)d_in[5];
  const float* Wv  = (const float*)d_in[6];
  const float* bv  = (const float*)d_in[7];
  const float* Wq  = (const float*)d_in[8];
  const float* bq  = (const float*)d_in[9];
  const float* Wo  = (const float*)d_in[10];
  const float* bo  = (const float*)d_in[11];
  const float* lng = (const float*)d_in[12];
  const float* lnb = (const float*)d_in[13];
  float* out = (float*)d_out;

  char* ws = (char*)d_ws;
  u16* hb = (u16*)ws;
  u16* kb = (u16*)(ws + 26214400);
  u16* vb = (u16*)(ws + 52428800);
  u16* qb = (u16*)(ws + 78643200);
  u16* xb = kb;  // alias: x-bf16 only needed before first K-projection

  // embed: xb = bf16(x); H0 = [cls, x@We+be] (fp32 in d_out, bf16 in hb)
  cast_kernel<<<1536, 256, 0, stream>>>(x, xb, 393216);
  cls_kernel<<<512, 256, 0, stream>>>(cls, out, hb);
  gemm_bias<<<dim3(8, 4, 24), 256, 0, stream>>>(
      xb, 1536, 64, We, 32768, 512, be, 512,
      hb + 512, out + 512, 12800, 512, 64);

  for (int l = 0; l < 6; ++l) {
    const float* Wk_l = Wk + (long)l * 262144;
    const float* Wv_l = Wv + (long)l * 262144;
    const float* Wq_l = Wq + (long)l * 6553600;
    const float* Wo_l = Wo + (long)l * 262144;
    // K = hb @ Wk + bk  -> kb
    gemm_bias<<<dim3(200, 4, 1), 256, 0, stream>>>(
        hb, 512, 0, Wk_l, 0, 512, bk + l * 512, 0, kb, nullptr, 512, 0, 512);
    // V -> vb
    gemm_bias<<<dim3(200, 4, 1), 256, 0, stream>>>(
        hb, 512, 0, Wv_l, 0, 512, bv + l * 512, 0, vb, nullptr, 512, 0, 512);
    // Q (per-joint grouped) -> qb
    gemm_bias<<<dim3(8, 4, 25), 256, 0, stream>>>(
        hb, 12800, 512, Wq_l, 262144, 512, bq + (long)l * 12800, 512,
        qb, nullptr, 12800, 512, 512);
    // attention: reads qb/kb/vb, writes attn-out over kb
    attn_kernel<<<1024, 256, 0, stream>>>(qb, kb, vb);
    // O-proj: kb @ Wo + bo -> qb (bf16)
    gemm_bias<<<dim3(200, 4, 1), 256, 0, stream>>>(
        kb, 512, 0, Wo_l, 0, 512, bo + l * 512, 0, qb, nullptr, 512, 0, 512);
    // h = LN(h + o): d_out (fp32) in place + bf16 shadow -> hb
    ln_kernel<<<6400, 256, 0, stream>>>(out, qb, lng + l * 512, lnb + l * 512, hb);
  }
}

// Round 2
// 1487.118 us; speedup vs baseline: 1.3884x; 1.3884x over previous
//
#include <hip/hip_runtime.h>

typedef unsigned short u16;
typedef unsigned int u32;
typedef short bf16x8 __attribute__((ext_vector_type(8)));
typedef float f32x4 __attribute__((ext_vector_type(4)));

__device__ __forceinline__ u16 f2b(float f) {
  u32 u = __float_as_uint(f);
  u += 0x7fffu + ((u >> 16) & 1u);   // round-to-nearest-even
  return (u16)(u >> 16);
}
__device__ __forceinline__ float b2f(u16 s) {
  return __uint_as_float(((u32)s) << 16);
}

// ---------------- cast x (f32) -> bf16 ----------------
__global__ __launch_bounds__(256) void cast_kernel(const float* __restrict__ x,
                                                   u16* __restrict__ xb, int n4) {
  int i = blockIdx.x * 256 + threadIdx.x;
  if (i >= n4) return;
  float4 v = ((const float4*)x)[i];
  ushort4 u;
  u.x = f2b(v.x); u.y = f2b(v.y); u.z = f2b(v.z); u.w = f2b(v.w);
  ((ushort4*)xb)[i] = u;
}

// ---------------- fill cls rows (token 0) ----------------
__global__ __launch_bounds__(256) void cls_kernel(const float* __restrict__ cls,
                                                  float* __restrict__ h,
                                                  u16* __restrict__ hb) {
  int i = blockIdx.x * 256 + threadIdx.x;  // B*128 threads, 4 elems each
  int b = i >> 7;
  int e = (i & 127) << 2;
  float4 v = *(const float4*)(cls + e);
  long off = (long)b * (25 * 512) + e;
  *(float4*)(h + off) = v;
  ushort4 u;
  u.x = f2b(v.x); u.y = f2b(v.y); u.z = f2b(v.z); u.w = f2b(v.w);
  *(ushort4*)(hb + off) = u;
}

// ---------------- generic grouped GEMM + bias ----------------
// C[row, col] = sum_k A[row*a_stride + g*a_goff + k] * W_g[k, col] + bias_g[col]
// 128x128 tile, 4 waves (each 64x64 = 4x4 frags of 16x16), BK=64.
// A is bf16; W/bias fp32 (converted to bf16 during staging).
// Writes bf16 to Cb always; optionally fp32 to Cf.
__global__ __launch_bounds__(256) void gemm_bias(
    const u16* __restrict__ Abase, long a_stride, long a_goff,
    const float* __restrict__ Wbase, long w_gstride, int ldw,
    const float* __restrict__ biasbase, long bias_gstride,
    u16* __restrict__ Cb, float* __restrict__ Cf, long c_stride, long c_goff,
    int K) {
  __shared__ u16 As[128 * 64];  // [row][k], XOR-swizzled (bits 3..5 of u16 idx)
  __shared__ u16 Bs[128 * 64];  // [col][k] (transposed), XOR-swizzled

  const int tid = threadIdx.x;
  const int lane = tid & 63;
  const int wave = tid >> 6;
  const int wr = wave >> 1, wc = wave & 1;
  const int m0 = blockIdx.x * 128;
  const int n0 = blockIdx.y * 128;
  const int g = blockIdx.z;

  const u16* Ag = Abase + (long)g * a_goff;
  const float* Wg = Wbase + (long)g * w_gstride;
  const float* biasg = biasbase + (long)g * bias_gstride;
  const long cg = (long)g * c_goff;

  const int ar = tid >> 1;           // A staging: row 0..127
  const int aks = (tid & 1) << 5;    // k-seg 0 / 32
  const int bc = tid & 127;          // B staging: col 0..127
  const int bks = (tid >> 7) << 5;   // k-seg 0 / 32

  f32x4 acc[4][4];
#pragma unroll
  for (int m = 0; m < 4; ++m)
#pragma unroll
    for (int n = 0; n < 4; ++n) {
      acc[m][n][0] = 0.f; acc[m][n][1] = 0.f;
      acc[m][n][2] = 0.f; acc[m][n][3] = 0.f;
    }

  for (int k0 = 0; k0 < K; k0 += 64) {
    // ---- global loads (before barrier, overlap with prior compute) ----
    const u16* asrc = Ag + (long)(m0 + ar) * a_stride + k0 + aks;
    uint4 a0 = *(const uint4*)(asrc + 0);
    uint4 a1 = *(const uint4*)(asrc + 8);
    uint4 a2 = *(const uint4*)(asrc + 16);
    uint4 a3 = *(const uint4*)(asrc + 24);

    const float* wsrc = Wg + (long)(k0 + bks) * ldw + n0 + bc;
    u32 pack[16];
#pragma unroll
    for (int i = 0; i < 16; ++i) {
      float f0 = wsrc[(long)(2 * i) * ldw];
      float f1 = wsrc[(long)(2 * i + 1) * ldw];
      pack[i] = (u32)f2b(f0) | ((u32)f2b(f1) << 16);
    }

    __syncthreads();  // previous tile's compute done (LDS free)
    {
      const int abase = ar << 6;
      const int asw = (ar & 7) << 3;
      *(uint4*)&As[(abase + aks + 0) ^ asw] = a0;
      *(uint4*)&As[(abase + aks + 8) ^ asw] = a1;
      *(uint4*)&As[(abase + aks + 16) ^ asw] = a2;
      *(uint4*)&As[(abase + aks + 24) ^ asw] = a3;
      const int bbase = bc << 6;
      const int bsw = (bc & 7) << 3;
#pragma unroll
      for (int i = 0; i < 4; ++i) {
        uint4 w;
        w.x = pack[4 * i + 0]; w.y = pack[4 * i + 1];
        w.z = pack[4 * i + 2]; w.w = pack[4 * i + 3];
        *(uint4*)&Bs[(bbase + bks + 8 * i) ^ bsw] = w;
      }
    }
    __syncthreads();  // tile ready

#pragma unroll
    for (int kk = 0; kk < 64; kk += 32) {
      const int kb = kk + ((lane >> 4) << 3);
      bf16x8 af[4], bfr[4];
#pragma unroll
      for (int m = 0; m < 4; ++m) {
        const int R = (wr << 6) + (m << 4) + (lane & 15);
        af[m] = *(const bf16x8*)&As[((R << 6) + kb) ^ ((R & 7) << 3)];
      }
#pragma unroll
      for (int n = 0; n < 4; ++n) {
        const int Cc = (wc << 6) + (n << 4) + (lane & 15);
        bfr[n] = *(const bf16x8*)&Bs[((Cc << 6) + kb) ^ ((Cc & 7) << 3)];
      }
#pragma unroll
      for (int m = 0; m < 4; ++m)
#pragma unroll
        for (int n = 0; n < 4; ++n)
          acc[m][n] = __builtin_amdgcn_mfma_f32_16x16x32_bf16(af[m], bfr[n],
                                                              acc[m][n], 0, 0, 0);
    }
  }

  // ---- epilogue: C/D layout col=lane&15, row=(lane>>4)*4+j (HW-verified) ----
  const int lcol = lane & 15;
  const int lrow = (lane >> 4) << 2;
#pragma unroll
  for (int n = 0; n < 4; ++n) {
    const int col = n0 + (wc << 6) + (n << 4) + lcol;
    const float bv = biasg[col];
#pragma unroll
    for (int m = 0; m < 4; ++m) {
      const int row = m0 + (wr << 6) + (m << 4) + lrow;
#pragma unroll
      for (int j = 0; j < 4; ++j) {
        const float val = acc[m][n][j] + bv;
        const long off = (long)(row + j) * c_stride + cg + col;
        Cb[off] = f2b(val);
        if (Cf) Cf[off] = val;
      }
    }
  }
}

// ---------------- attention v2: wave per (batch, head) ----------------
// Block = 256 threads = 4 waves = 4 heads; blockIdx.x = b*2 + h0 covers
// heads h0*4..h0*4+3. Lane = (qi, half): qi = lane>>1 (rows 0..24 active),
// half = lane&1 owns a 32-elem d-slice. K,V staged in LDS (bf16, [25][256]).
// Scores: per-lane 32-d partial dot + shfl_xor(1) combine -> each lane holds
// the full 25-score row in registers; softmax in-register; PV over its slice.
// Writes output over the K buffer.
__global__ __launch_bounds__(256) void attn_kernel(const u16* __restrict__ q,
                                                   u16* __restrict__ kio,
                                                   const u16* __restrict__ v) {
  __shared__ u16 ks_[25 * 256];
  __shared__ u16 vs_[25 * 256];
  const int tid = threadIdx.x;
  const int b = blockIdx.x >> 1;
  const int h0 = blockIdx.x & 1;      // head-group (4 heads)
  const long base = (long)b * 25 * 512;

  // ---- stage K, V slices for this head-group: 25 rows x 256 elems each ----
  // chunk i -> row j = i>>5, 16B-chunk c = i&31
  for (int i = tid; i < 800; i += 256) {
    const int j = i >> 5, c = i & 31;
    const long goff = base + (long)j * 512 + h0 * 256 + c * 8;
    ((uint4*)ks_)[i] = *(const uint4*)(kio + goff);
    ((uint4*)vs_)[i] = *(const uint4*)(v + goff);
  }
  __syncthreads();

  const int w = tid >> 6;             // wave = head-within-group
  const int lane = tid & 63;
  const int qi = lane >> 1;
  const int half = lane & 1;
  if (qi < 25) {
    const int h = h0 * 4 + w;
    const int dslice = w * 64 + half * 32;   // offset within [256] LDS row

    // load Q slice (32 bf16 -> fp32)
    const u16* qrow = q + base + (long)qi * 512 + h * 64 + half * 32;
    float buf[32];
#pragma unroll
    for (int c = 0; c < 4; ++c) {
      uint4 t = *(const uint4*)(qrow + c * 8);
      const u32 tt[4] = {t.x, t.y, t.z, t.w};
#pragma unroll
      for (int e = 0; e < 4; ++e) {
        buf[c * 8 + 2 * e]     = b2f((u16)tt[e]);
        buf[c * 8 + 2 * e + 1] = b2f((u16)(tt[e] >> 16));
      }
    }

    // scores
    float sc[25];
    float mx = -1e30f;
#pragma unroll
    for (int j = 0; j < 25; ++j) {
      float s = 0.f;
      const u16* kr = &ks_[j * 256 + dslice];
#pragma unroll
      for (int d = 0; d < 32; d += 2) {
        u32 t = *(const u32*)(kr + d);
        s += buf[d] * b2f((u16)t) + buf[d + 1] * b2f((u16)(t >> 16));
      }
      s += __shfl_xor(s, 1);          // combine the two 32-d halves
      s *= 0.125f;                    // 1/sqrt(64)
      sc[j] = s;
      mx = fmaxf(mx, s);
    }
    float sum = 0.f;
#pragma unroll
    for (int j = 0; j < 25; ++j) {
      sc[j] = __expf(sc[j] - mx);
      sum += sc[j];
    }
    const float inv = 1.f / sum;

    // PV over this lane's 32-d slice (reuse buf as accumulator)
#pragma unroll
    for (int d = 0; d < 32; ++d) buf[d] = 0.f;
#pragma unroll
    for (int j = 0; j < 25; ++j) {
      const float wj = sc[j];
      const u16* vr = &vs_[j * 256 + dslice];
#pragma unroll
      for (int d = 0; d < 32; d += 2) {
        u32 t = *(const u32*)(vr + d);
        buf[d]     += wj * b2f((u16)t);
        buf[d + 1] += wj * b2f((u16)(t >> 16));
      }
    }

    // write output slice (over K buffer)
    u16* orow = kio + base + (long)qi * 512 + h * 64 + half * 32;
#pragma unroll
    for (int c = 0; c < 4; ++c) {
      uint4 t;
      u32 tt[4];
#pragma unroll
      for (int e = 0; e < 4; ++e)
        tt[e] = (u32)f2b(buf[c * 8 + 2 * e] * inv) |
                ((u32)f2b(buf[c * 8 + 2 * e + 1] * inv) << 16);
      t.x = tt[0]; t.y = tt[1]; t.z = tt[2]; t.w = tt[3];
      *(uint4*)(orow + c * 8) = t;
    }
  }
}

// ---------------- residual + LayerNorm: wave per row ----------------
// h(f32, in/out d_out) += o(bf16); LN; writes f32 back + bf16 shadow to hb.
__global__ __launch_bounds__(256) void ln_kernel(float* __restrict__ h,
                                                 const u16* __restrict__ o,
                                                 const float* __restrict__ g,
                                                 const float* __restrict__ bta,
                                                 u16* __restrict__ hb) {
  const int lane = threadIdx.x & 63;
  const int wave = threadIdx.x >> 6;
  const long row = (long)blockIdx.x * 4 + wave;
  float* hr = h + row * 512;
  const u16* orow = o + row * 512;
  const int base = lane << 3;
  float4 h0 = *(const float4*)(hr + base);
  float4 h1 = *(const float4*)(hr + base + 4);
  uint4 ov = *(const uint4*)(orow + base);
  float y[8];
  y[0] = h0.x + b2f((u16)ov.x); y[1] = h0.y + b2f((u16)(ov.x >> 16));
  y[2] = h0.z + b2f((u16)ov.y); y[3] = h0.w + b2f((u16)(ov.y >> 16));
  y[4] = h1.x + b2f((u16)ov.z); y[5] = h1.y + b2f((u16)(ov.z >> 16));
  y[6] = h1.z + b2f((u16)ov.w); y[7] = h1.w + b2f((u16)(ov.w >> 16));
  float s = 0.f, ss = 0.f;
#pragma unroll
  for (int i = 0; i < 8; ++i) { s += y[i]; ss += y[i] * y[i]; }
#pragma unroll
  for (int off = 32; off > 0; off >>= 1) {
    s += __shfl_down(s, off);
    ss += __shfl_down(ss, off);
  }
  s = __shfl(s, 0);
  ss = __shfl(ss, 0);
  const float mean = s * (1.f / 512.f);
  const float var = ss * (1.f / 512.f) - mean * mean;
  const float rinv = rsqrtf(var + 1e-5f);
  float4 g0 = *(const float4*)(g + base);
  float4 g1 = *(const float4*)(g + base + 4);
  float4 b0 = *(const float4*)(bta + base);
  float4 b1 = *(const float4*)(bta + base + 4);
  float r[8];
  r[0] = (y[0] - mean) * rinv * g0.x + b0.x;
  r[1] = (y[1] - mean) * rinv * g0.y + b0.y;
  r[2] = (y[2] - mean) * rinv * g0.z + b0.z;
  r[3] = (y[3] - mean) * rinv * g0.w + b0.w;
  r[4] = (y[4] - mean) * rinv * g1.x + b1.x;
  r[5] = (y[5] - mean) * rinv * g1.y + b1.y;
  r[6] = (y[6] - mean) * rinv * g1.z + b1.z;
  r[7] = (y[7] - mean) * rinv * g1.w + b1.w;
  float4 w0 = {r[0], r[1], r[2], r[3]};
  float4 w1 = {r[4], r[5], r[6], r[7]};
  *(float4*)(hr + base) = w0;
  *(float4*)(hr + base + 4) = w1;
  uint4 hv;
  hv.x = (u32)f2b(r[0]) | ((u32)f2b(r[1]) << 16);
  hv.y = (u32)f2b(r[2]) | ((u32)f2b(r[3]) << 16);
  hv.z = (u32)f2b(r[4]) | ((u32)f2b(r[5]) << 16);
  hv.w = (u32)f2b(r[6]) | ((u32)f2b(r[7]) << 16);
  *(uint4*)(hb + row * 512 + base) = hv;
}

// ---------------- host launcher ----------------
// d_in order: x, We, be, cls, Wk, bk, Wv, bv, Wq, bq, Wo, bo, ln_g, ln_b
// Workspace plan (needs 100 MiB):
//   hb (bf16 H)   @ 0          : 26,214,400 B
//   kb (bf16 K/AO)@ 26,214,400 : 26,214,400 B   (also aliased as xb pre-layers)
//   vb (bf16 V)   @ 52,428,800 : 26,214,400 B
//   qb (bf16 Q/O) @ 78,643,200 : 26,214,400 B
extern "C" void kernel_launch(void* const* d_in, const int* in_sizes, int n_in,
                              void* d_out, int out_size, void* d_ws, size_t ws_size,
                              hipStream_t stream) {
  const float* x   = (const float*)d_in[0];
  const float* We  = (const float*)d_in[1];
  const float* be  = (const float*)d_in[2];
  const float* cls = (const float*)d_in[3];
  const float* Wk  = (const float*)d_in[4];
  const float* bk  = (const float*)d_in[5];
  const float* Wv  = (const float*)d_in[6];
  const float* bv  = (const float*)d_in[7];
  const float* Wq  = (const float*)d_in[8];
  const float* bq  = (const float*)d_in[9];
  const float* Wo  = (const float*)d_in[10];
  const float* bo  = (const float*)d_in[11];
  const float* lng = (const float*)d_in[12];
  const float* lnb = (const float*)d_in[13];
  float* out = (float*)d_out;

  char* ws = (char*)d_ws;
  u16* hb = (u16*)ws;
  u16* kb = (u16*)(ws + 26214400);
  u16* vb = (u16*)(ws + 52428800);
  u16* qb = (u16*)(ws + 78643200);
  u16* xb = kb;  // alias: x-bf16 only needed before first K-projection

  // embed: xb = bf16(x); H0 = [cls, x@We+be] (fp32 in d_out, bf16 in hb)
  cast_kernel<<<1536, 256, 0, stream>>>(x, xb, 393216);
  cls_kernel<<<512, 256, 0, stream>>>(cls, out, hb);
  gemm_bias<<<dim3(8, 4, 24), 256, 0, stream>>>(
      xb, 1536, 64, We, 32768, 512, be, 512,
      hb + 512, out + 512, 12800, 512, 64);

  for (int l = 0; l < 6; ++l) {
    const float* Wk_l = Wk + (long)l * 262144;
    const float* Wv_l = Wv + (long)l * 262144;
    const float* Wq_l = Wq + (long)l * 6553600;
    const float* Wo_l = Wo + (long)l * 262144;
    // K = hb @ Wk + bk  -> kb
    gemm_bias<<<dim3(200, 4, 1), 256, 0, stream>>>(
        hb, 512, 0, Wk_l, 0, 512, bk + l * 512, 0, kb, nullptr, 512, 0, 512);
    // V -> vb
    gemm_bias<<<dim3(200, 4, 1), 256, 0, stream>>>(
        hb, 512, 0, Wv_l, 0, 512, bv + l * 512, 0, vb, nullptr, 512, 0, 512);
    // Q (per-joint grouped) -> qb
    gemm_bias<<<dim3(8, 4, 25), 256, 0, stream>>>(
        hb, 12800, 512, Wq_l, 262144, 512, bq + (long)l * 12800, 512,
        qb, nullptr, 12800, 512, 512);
    // attention: reads qb/kb/vb, writes attn-out over kb
    attn_kernel<<<2048, 256, 0, stream>>>(qb, kb, vb);
    // O-proj: kb @ Wo + bo -> qb (bf16)
    gemm_bias<<<dim3(200, 4, 1), 256, 0, stream>>>(
        kb, 512, 0, Wo_l, 0, 512, bo + l * 512, 0, qb, nullptr, 512, 0, 512);
    // h = LN(h + o): d_out (fp32) in place + bf16 shadow -> hb
    ln_kernel<<<6400, 256, 0, stream>>>(out, qb, lng + l * 512, lnb + l * 512, hb);
  }
}

// Round 3
// 1113.314 us; speedup vs baseline: 1.8546x; 1.3358x over previous
//
#include <hip/hip_runtime.h>

typedef unsigned short u16;
typedef unsigned int u32;
typedef short bf16x8 __attribute__((ext_vector_type(8)));
typedef float f32x4 __attribute__((ext_vector_type(4)));

#define AS1 __attribute__((address_space(1)))
#define AS3 __attribute__((address_space(3)))

__device__ __forceinline__ u16 f2b(float f) {
  u32 u = __float_as_uint(f);
  u += 0x7fffu + ((u >> 16) & 1u);   // round-to-nearest-even
  return (u16)(u >> 16);
}
__device__ __forceinline__ float b2f(u16 s) {
  return __uint_as_float(((u32)s) << 16);
}

__device__ __forceinline__ void gload16(const u16* g, u16* l) {
  __builtin_amdgcn_global_load_lds((const AS1 void*)g, (AS3 void*)l, 16, 0, 0);
}

// ---------------- cast x (f32) -> bf16 ----------------
__global__ __launch_bounds__(256) void cast_kernel(const float* __restrict__ x,
                                                   u16* __restrict__ xb, int n4) {
  int i = blockIdx.x * 256 + threadIdx.x;
  if (i >= n4) return;
  float4 v = ((const float4*)x)[i];
  ushort4 u;
  u.x = f2b(v.x); u.y = f2b(v.y); u.z = f2b(v.z); u.w = f2b(v.w);
  ((ushort4*)xb)[i] = u;
}

// ---------------- fill cls rows (token 0, bf16 residual) ----------------
__global__ __launch_bounds__(256) void cls_kernel(const float* __restrict__ cls,
                                                  u16* __restrict__ hb) {
  int i = blockIdx.x * 256 + threadIdx.x;  // B*128 threads, 4 elems each
  int b = i >> 7;
  int e = (i & 127) << 2;
  float4 v = *(const float4*)(cls + e);
  long off = (long)b * (25 * 512) + e;
  ushort4 u;
  u.x = f2b(v.x); u.y = f2b(v.y); u.z = f2b(v.z); u.w = f2b(v.w);
  *(ushort4*)(hb + off) = u;
}

// ---------------- transpose+convert: dst[n][k] (bf16) = src[k][n] (f32) ------
// 64x64 tile per block; grid (K/64, N/64, groups)
__global__ __launch_bounds__(256) void convT_kernel(const float* __restrict__ src,
                                                    u16* __restrict__ dst,
                                                    int K, int N,
                                                    long src_gstride, long dst_gstride) {
  __shared__ float t[64][65];
  const int k0 = blockIdx.x * 64, n0 = blockIdx.y * 64;
  const float* s = src + (long)blockIdx.z * src_gstride;
  u16* d = dst + (long)blockIdx.z * dst_gstride;
  for (int i = threadIdx.x; i < 4096; i += 256) {
    int r = i >> 6, c = i & 63;
    t[r][c] = s[(long)(k0 + r) * N + n0 + c];
  }
  __syncthreads();
  for (int i = threadIdx.x; i < 4096; i += 256) {
    int r = i >> 6, c = i & 63;  // r = n-local, c = k-local
    d[(long)(n0 + r) * K + k0 + c] = f2b(t[c][r]);
  }
}

// ---- fused per-layer weight convert: Wq(25 groups) + Wk + Wv + Wo, 512x512 ----
__global__ __launch_bounds__(256) void convT4_kernel(
    const float* __restrict__ wq, const float* __restrict__ wk,
    const float* __restrict__ wv, const float* __restrict__ wo,
    u16* __restrict__ dq, u16* __restrict__ dk,
    u16* __restrict__ dv, u16* __restrict__ dwo) {
  __shared__ float t[64][65];
  const int z = blockIdx.z;
  const float* src;
  u16* dst;
  if (z < 25)      { src = wq + (long)z * 262144; dst = dq + (long)z * 262144; }
  else if (z == 25){ src = wk; dst = dk; }
  else if (z == 26){ src = wv; dst = dv; }
  else             { src = wo; dst = dwo; }
  const int k0 = blockIdx.x * 64, n0 = blockIdx.y * 64;
  for (int i = threadIdx.x; i < 4096; i += 256) {
    int r = i >> 6, c = i & 63;
    t[r][c] = src[(long)(k0 + r) * 512 + n0 + c];
  }
  __syncthreads();
  for (int i = threadIdx.x; i < 4096; i += 256) {
    int r = i >> 6, c = i & 63;
    dst[(long)(n0 + r) * 512 + k0 + c] = f2b(t[c][r]);
  }
}

// ---------------- GEMM core: C = A @ Wt^T + bias ----------------
// A: bf16 [M][K] rows at a_stride; Wt: bf16 [N][K] row-major (pre-transposed).
// 128x128 tile, 4 waves, BK=64, m97 structure: global_load_lds(16B) both
// operands, source-side XOR swizzle (chunk ^= row&7), 2 barriers per K-step.
__device__ __forceinline__ void gemm_core(u16* As, u16* Bs,
    const u16* Ag, long a_stride, const u16* Wg, const float* biasg,
    u16* Cg, long c_stride, int K, int m0, int n0) {
  const int tid = threadIdx.x;
  const int lane = tid & 63;
  const int wave = tid >> 6;
  const int wr = wave >> 1, wc = wave & 1;

  // staging: wave covers 32 rows (4 instrs x 8 rows); lane -> row lane>>3, chunk lane&7
  const int schunk = lane & 7;
  const u16* ga[4];
  const u16* gb[4];
  u16* la[4];
  u16* lb[4];
#pragma unroll
  for (int i = 0; i < 4; ++i) {
    const int r = wave * 32 + i * 8 + (lane >> 3);
    const int csw = (schunk ^ (r & 7)) << 3;
    ga[i] = Ag + (long)(m0 + r) * a_stride + csw;
    gb[i] = Wg + (long)(n0 + r) * K + csw;
    la[i] = &As[(wave * 32 + i * 8) * 64];
    lb[i] = &Bs[(wave * 32 + i * 8) * 64];
  }

  f32x4 acc[4][4];
#pragma unroll
  for (int m = 0; m < 4; ++m)
#pragma unroll
    for (int n = 0; n < 4; ++n) {
      acc[m][n][0] = 0.f; acc[m][n][1] = 0.f;
      acc[m][n][2] = 0.f; acc[m][n][3] = 0.f;
    }

  for (int k0 = 0; k0 < K; k0 += 64) {
    __syncthreads();  // WAR: previous tile's ds_reads complete
#pragma unroll
    for (int i = 0; i < 4; ++i) {
      gload16(ga[i] + k0, la[i]);
      gload16(gb[i] + k0, lb[i]);
    }
    __syncthreads();  // drains vmcnt(0): tile resident

#pragma unroll
    for (int kk = 0; kk < 64; kk += 32) {
      const int kb = kk + ((lane >> 4) << 3);
      bf16x8 af[4], bfr[4];
#pragma unroll
      for (int m = 0; m < 4; ++m) {
        const int R = (wr << 6) + (m << 4) + (lane & 15);
        af[m] = *(const bf16x8*)&As[((R << 6) + kb) ^ ((R & 7) << 3)];
      }
#pragma unroll
      for (int n = 0; n < 4; ++n) {
        const int Cc = (wc << 6) + (n << 4) + (lane & 15);
        bfr[n] = *(const bf16x8*)&Bs[((Cc << 6) + kb) ^ ((Cc & 7) << 3)];
      }
#pragma unroll
      for (int m = 0; m < 4; ++m)
#pragma unroll
        for (int n = 0; n < 4; ++n)
          acc[m][n] = __builtin_amdgcn_mfma_f32_16x16x32_bf16(af[m], bfr[n],
                                                              acc[m][n], 0, 0, 0);
    }
  }

  // epilogue: C/D layout col=lane&15, row=(lane>>4)*4+j (HW-verified)
  const int lcol = lane & 15;
  const int lrow = (lane >> 4) << 2;
#pragma unroll
  for (int n = 0; n < 4; ++n) {
    const int col = n0 + (wc << 6) + (n << 4) + lcol;
    const float bv = biasg[col];
#pragma unroll
    for (int m = 0; m < 4; ++m) {
      const int row = m0 + (wr << 6) + (m << 4) + lrow;
#pragma unroll
      for (int j = 0; j < 4; ++j) {
        const float val = acc[m][n][j] + bv;
        Cg[(long)(row + j) * c_stride + col] = f2b(val);
      }
    }
  }
}

// plain grouped wrapper: grid (mtiles, ntiles, groups)
__global__ __launch_bounds__(256) void gemm_plain(
    const u16* __restrict__ Abase, long a_stride, long a_goff,
    const u16* __restrict__ Wbase, long w_gstride,
    const float* __restrict__ biasbase, long bias_gstride,
    u16* __restrict__ Cb, long c_stride, long c_goff, int K) {
  __shared__ u16 As[128 * 64];
  __shared__ u16 Bs[128 * 64];
  const int g = blockIdx.z;
  gemm_core(As, Bs,
            Abase + (long)g * a_goff, a_stride,
            Wbase + (long)g * w_gstride,
            biasbase + (long)g * bias_gstride,
            Cb + (long)g * c_goff, c_stride, K,
            blockIdx.x * 128, blockIdx.y * 128);
}

// fused Q(25 groups)+K+V: 1D grid of 2400 blocks
__global__ __launch_bounds__(256) void gemm_qkv(
    const u16* __restrict__ hb,
    const u16* __restrict__ wqT, const u16* __restrict__ wkT, const u16* __restrict__ wvT,
    const float* __restrict__ bq, const float* __restrict__ bk, const float* __restrict__ bv,
    u16* __restrict__ qb, u16* __restrict__ kb, u16* __restrict__ vb) {
  __shared__ u16 As[128 * 64];
  __shared__ u16 Bs[128 * 64];
  const int bid = blockIdx.x;
  const u16* Ag; long a_str; const u16* Wg; const float* bg; u16* Cg; long c_str;
  int mt, nt;
  if (bid < 800) {           // Q: per-joint groups
    const int g = bid >> 5, rem = bid & 31;
    mt = rem >> 2; nt = rem & 3;
    Ag = hb + (long)g * 512; a_str = 12800;
    Wg = wqT + (long)g * 262144; bg = bq + (long)g * 512;
    Cg = qb + (long)g * 512; c_str = 12800;
  } else if (bid < 1600) {   // K
    const int rem = bid - 800;
    mt = rem >> 2; nt = rem & 3;
    Ag = hb; a_str = 512; Wg = wkT; bg = bk; Cg = kb; c_str = 512;
  } else {                   // V
    const int rem = bid - 1600;
    mt = rem >> 2; nt = rem & 3;
    Ag = hb; a_str = 512; Wg = wvT; bg = bv; Cg = vb; c_str = 512;
  }
  gemm_core(As, Bs, Ag, a_str, Wg, bg, Cg, c_str, 512, mt * 128, nt * 128);
}

// ---------------- attention: wave per (batch, head) ----------------
__global__ __launch_bounds__(256) void attn_kernel(const u16* __restrict__ q,
                                                   u16* __restrict__ kio,
                                                   const u16* __restrict__ v) {
  __shared__ u16 ks_[25 * 256];
  __shared__ u16 vs_[25 * 256];
  const int tid = threadIdx.x;
  const int b = blockIdx.x >> 1;
  const int h0 = blockIdx.x & 1;      // head-group (4 heads)
  const long base = (long)b * 25 * 512;

  for (int i = tid; i < 800; i += 256) {
    const int j = i >> 5, c = i & 31;
    const long goff = base + (long)j * 512 + h0 * 256 + c * 8;
    ((uint4*)ks_)[i] = *(const uint4*)(kio + goff);
    ((uint4*)vs_)[i] = *(const uint4*)(v + goff);
  }
  __syncthreads();

  const int w = tid >> 6;
  const int lane = tid & 63;
  const int qi = lane >> 1;
  const int half = lane & 1;
  if (qi < 25) {
    const int h = h0 * 4 + w;
    const int dslice = w * 64 + half * 32;

    const u16* qrow = q + base + (long)qi * 512 + h * 64 + half * 32;
    float buf[32];
#pragma unroll
    for (int c = 0; c < 4; ++c) {
      uint4 t = *(const uint4*)(qrow + c * 8);
      const u32 tt[4] = {t.x, t.y, t.z, t.w};
#pragma unroll
      for (int e = 0; e < 4; ++e) {
        buf[c * 8 + 2 * e]     = b2f((u16)tt[e]);
        buf[c * 8 + 2 * e + 1] = b2f((u16)(tt[e] >> 16));
      }
    }

    float sc[25];
    float mx = -1e30f;
#pragma unroll
    for (int j = 0; j < 25; ++j) {
      float s = 0.f;
      const u16* kr = &ks_[j * 256 + dslice];
#pragma unroll
      for (int d = 0; d < 32; d += 2) {
        u32 t = *(const u32*)(kr + d);
        s += buf[d] * b2f((u16)t) + buf[d + 1] * b2f((u16)(t >> 16));
      }
      s += __shfl_xor(s, 1);
      s *= 0.125f;
      sc[j] = s;
      mx = fmaxf(mx, s);
    }
    float sum = 0.f;
#pragma unroll
    for (int j = 0; j < 25; ++j) {
      sc[j] = __expf(sc[j] - mx);
      sum += sc[j];
    }
    const float inv = 1.f / sum;

#pragma unroll
    for (int d = 0; d < 32; ++d) buf[d] = 0.f;
#pragma unroll
    for (int j = 0; j < 25; ++j) {
      const float wj = sc[j];
      const u16* vr = &vs_[j * 256 + dslice];
#pragma unroll
      for (int d = 0; d < 32; d += 2) {
        u32 t = *(const u32*)(vr + d);
        buf[d]     += wj * b2f((u16)t);
        buf[d + 1] += wj * b2f((u16)(t >> 16));
      }
    }

    u16* orow = kio + base + (long)qi * 512 + h * 64 + half * 32;
#pragma unroll
    for (int c = 0; c < 4; ++c) {
      uint4 t;
      u32 tt[4];
#pragma unroll
      for (int e = 0; e < 4; ++e)
        tt[e] = (u32)f2b(buf[c * 8 + 2 * e] * inv) |
                ((u32)f2b(buf[c * 8 + 2 * e + 1] * inv) << 16);
      t.x = tt[0]; t.y = tt[1]; t.z = tt[2]; t.w = tt[3];
      *(uint4*)(orow + c * 8) = t;
    }
  }
}

// ---------------- residual + LayerNorm (bf16 residual) ----------------
// y = hb[row] + o[row]; LN; write hb (bf16) and optionally fout (fp32, final).
__global__ __launch_bounds__(256) void ln_kernel(u16* hb,
                                                 const u16* __restrict__ o,
                                                 const float* __restrict__ g,
                                                 const float* __restrict__ bta,
                                                 float* fout) {
  const int lane = threadIdx.x & 63;
  const int wave = threadIdx.x >> 6;
  const long row = (long)blockIdx.x * 4 + wave;
  u16* hr = hb + row * 512;
  const u16* orow = o + row * 512;
  const int base = lane << 3;
  uint4 hv4 = *(const uint4*)(hr + base);
  uint4 ov = *(const uint4*)(orow + base);
  const u32 ha[4] = {hv4.x, hv4.y, hv4.z, hv4.w};
  const u32 oa[4] = {ov.x, ov.y, ov.z, ov.w};
  float y[8];
#pragma unroll
  for (int e = 0; e < 4; ++e) {
    y[2 * e]     = b2f((u16)ha[e])         + b2f((u16)oa[e]);
    y[2 * e + 1] = b2f((u16)(ha[e] >> 16)) + b2f((u16)(oa[e] >> 16));
  }
  float s = 0.f, ss = 0.f;
#pragma unroll
  for (int i = 0; i < 8; ++i) { s += y[i]; ss += y[i] * y[i]; }
#pragma unroll
  for (int off = 32; off > 0; off >>= 1) {
    s += __shfl_down(s, off);
    ss += __shfl_down(ss, off);
  }
  s = __shfl(s, 0);
  ss = __shfl(ss, 0);
  const float mean = s * (1.f / 512.f);
  const float var = ss * (1.f / 512.f) - mean * mean;
  const float rinv = rsqrtf(var + 1e-5f);
  float4 g0 = *(const float4*)(g + base);
  float4 g1 = *(const float4*)(g + base + 4);
  float4 b0 = *(const float4*)(bta + base);
  float4 b1 = *(const float4*)(bta + base + 4);
  float r[8];
  r[0] = (y[0] - mean) * rinv * g0.x + b0.x;
  r[1] = (y[1] - mean) * rinv * g0.y + b0.y;
  r[2] = (y[2] - mean) * rinv * g0.z + b0.z;
  r[3] = (y[3] - mean) * rinv * g0.w + b0.w;
  r[4] = (y[4] - mean) * rinv * g1.x + b1.x;
  r[5] = (y[5] - mean) * rinv * g1.y + b1.y;
  r[6] = (y[6] - mean) * rinv * g1.z + b1.z;
  r[7] = (y[7] - mean) * rinv * g1.w + b1.w;
  uint4 hv;
  hv.x = (u32)f2b(r[0]) | ((u32)f2b(r[1]) << 16);
  hv.y = (u32)f2b(r[2]) | ((u32)f2b(r[3]) << 16);
  hv.z = (u32)f2b(r[4]) | ((u32)f2b(r[5]) << 16);
  hv.w = (u32)f2b(r[6]) | ((u32)f2b(r[7]) << 16);
  *(uint4*)(hr + base) = hv;
  if (fout) {
    float* fr = fout + row * 512 + base;
    float4 w0 = {r[0], r[1], r[2], r[3]};
    float4 w1 = {r[4], r[5], r[6], r[7]};
    *(float4*)(fr) = w0;
    *(float4*)(fr + 4) = w1;
  }
}

// ---------------- host launcher ----------------
// d_in: x, We, be, cls, Wk, bk, Wv, bv, Wq, bq, Wo, bo, ln_g, ln_b
// ws (100 MiB): hb@0, kb@25M(=xb alias), vb@50M, qb@75M (u16 elems 13,107,200 ea)
// d_out doubles as weight scratch (bf16) during layers; final LN rewrites it.
extern "C" void kernel_launch(void* const* d_in, const int* in_sizes, int n_in,
                              void* d_out, int out_size, void* d_ws, size_t ws_size,
                              hipStream_t stream) {
  const float* x   = (const float*)d_in[0];
  const float* We  = (const float*)d_in[1];
  const float* be  = (const float*)d_in[2];
  const float* cls = (const float*)d_in[3];
  const float* Wk  = (const float*)d_in[4];
  const float* bk  = (const float*)d_in[5];
  const float* Wv  = (const float*)d_in[6];
  const float* bv  = (const float*)d_in[7];
  const float* Wq  = (const float*)d_in[8];
  const float* bq  = (const float*)d_in[9];
  const float* Wo  = (const float*)d_in[10];
  const float* bo  = (const float*)d_in[11];
  const float* lng = (const float*)d_in[12];
  const float* lnb = (const float*)d_in[13];
  float* out = (float*)d_out;

  char* ws = (char*)d_ws;
  u16* hb = (u16*)ws;
  u16* kb = (u16*)(ws + 26214400);
  u16* vb = (u16*)(ws + 52428800);
  u16* qb = (u16*)(ws + 78643200);
  u16* xb = kb;  // alias: consumed by embed GEMM before K written

  // weight scratch in d_out (bf16 view)
  u16* scr = (u16*)d_out;
  u16* weT = scr;                    // 786,432 elems (embed only)
  u16* wqT = scr;                    // 6,553,600
  u16* wkT = scr + 6553600;          // 262,144
  u16* wvT = scr + 6815744;          // 262,144
  u16* woT = scr + 7077888;          // 262,144  (total 14.7 MB < 52.4 MB)

  // prologue: cast x; cls rows; convert We^T; embed GEMM -> hb
  cast_kernel<<<1536, 256, 0, stream>>>(x, xb, 393216);
  cls_kernel<<<512, 256, 0, stream>>>(cls, hb);
  convT_kernel<<<dim3(1, 8, 24), 256, 0, stream>>>(We, weT, 64, 512, 32768, 32768);
  gemm_plain<<<dim3(8, 4, 24), 256, 0, stream>>>(
      xb, 1536, 64, weT, 32768, be, 512, hb + 512, 12800, 512, 64);

  for (int l = 0; l < 6; ++l) {
    convT4_kernel<<<dim3(8, 8, 28), 256, 0, stream>>>(
        Wq + (long)l * 6553600, Wk + (long)l * 262144,
        Wv + (long)l * 262144, Wo + (long)l * 262144,
        wqT, wkT, wvT, woT);
    gemm_qkv<<<2400, 256, 0, stream>>>(
        hb, wqT, wkT, wvT,
        bq + (long)l * 12800, bk + (long)l * 512, bv + (long)l * 512,
        qb, kb, vb);
    attn_kernel<<<2048, 256, 0, stream>>>(qb, kb, vb);
    gemm_plain<<<dim3(200, 4, 1), 256, 0, stream>>>(
        kb, 512, 0, woT, 0, bo + (long)l * 512, 0, qb, 512, 0, 512);
    ln_kernel<<<6400, 256, 0, stream>>>(hb, qb, lng + l * 512, lnb + l * 512,
                                        (l == 5) ? out : nullptr);
  }
}